// Round 4
// baseline (2731.786 us; speedup 1.0000x reference)
//
#include <hip/hip_runtime.h>

typedef unsigned short u16;
typedef unsigned int   u32;
typedef __bf16 bf16x8 __attribute__((ext_vector_type(8)));
typedef float  f32x4  __attribute__((ext_vector_type(4)));

#define DEVI __device__ __forceinline__

DEVI u16 f2bf(float f){
  u32 u = __builtin_bit_cast(u32, f);
  u32 r = (u + 0x7fffu + ((u >> 16) & 1u)) >> 16;   // RNE
  return (u16)r;
}

DEVI void gload16(const void* g, void* lds){
  __builtin_amdgcn_global_load_lds(
      (const __attribute__((address_space(1))) void*)g,
      (__attribute__((address_space(3))) void*)lds, 16, 0, 0);
}

DEVI f32x4 MFMA(bf16x8 a, bf16x8 b, f32x4 c){
  return __builtin_amdgcn_mfma_f32_16x16x32_bf16(a, b, c, 0, 0, 0);
}

// ---------------- mask dtype probe: 1 => uint8 bytes, 0 => int32 ----------------
__global__ void k_maskprobe(const unsigned char* __restrict__ m, int* __restrict__ flag){
  __shared__ int s;
  if (threadIdx.x == 0) s = 0;
  __syncthreads();
  int acc = 0;
  for (int i = threadIdx.x; i < 65536; i += 256)
    if ((i & 3) != 0 && m[i] != 0) acc++;
  atomicAdd(&s, acc);
  __syncthreads();
  if (threadIdx.x == 0) *flag = (s > 0) ? 1 : 0;
}

// ---------------- pack attn_mask to bitmask [B*S][16 words] ----------------
__global__ void k_maskbits(const void* __restrict__ mask, const int* __restrict__ flag,
                           u32* __restrict__ mb){
  int row  = blockIdx.x * 4 + (threadIdx.x >> 6);   // b*512+q
  int lane = threadIdx.x & 63;
  bool bytes = (*flag != 0);
  for (int c0 = 0; c0 < 512; c0 += 64){
    int v;
    if (bytes) v = ((const unsigned char*)mask)[(size_t)row * 512 + c0 + lane];
    else       v = ((const int*)mask)[(size_t)row * 512 + c0 + lane];
    unsigned long long bits = __ballot(v != 0);
    if (lane == 0){
      mb[(size_t)row * 16 + (c0 >> 5)]     = (u32)(bits & 0xffffffffull);
      mb[(size_t)row * 16 + (c0 >> 5) + 1] = (u32)(bits >> 32);
    }
  }
}

// ---------------- embedding gather ----------------
__global__ void k_embed(const int* __restrict__ ids, const float* __restrict__ wemb,
                        float* __restrict__ h){
  int row = blockIdx.x;
  const float* s = wemb + (size_t)ids[row] * 768;
  float* d = h + (size_t)row * 768;
  int t = threadIdx.x;
  d[t] = s[t]; d[t + 256] = s[t + 256]; d[t + 512] = s[t + 512];
}

// ---------------- node-average (rows with pos==0) ----------------
__global__ void k_nodeavg(const int* __restrict__ pos, const u32* __restrict__ mb,
                          float* __restrict__ h){
  int row = blockIdx.x;                 // b*512+n
  if (pos[row] != 0) return;
  int b = row >> 9;
  int c = blockIdx.y * 256 + threadIdx.x;
  const u32* mrow = mb + (size_t)row * 16;
  const int* pb = pos + ((size_t)b << 9);
  float a = 0.f, cnt = 0.f;
  #pragma unroll 4
  for (int t = 0; t < 512; t++){
    if (pb[t] >= 2 && ((mrow[t >> 5] >> (t & 31)) & 1)){
      a += h[(((size_t)b << 9) + t) * 768 + c];
      cnt += 1.f;
    }
  }
  h[(size_t)row * 768 + c] = a / (cnt + 1e-10f);
}

// ---------------- LN kernels ----------------
__global__ void k_ln0(const int* __restrict__ pos, const float* __restrict__ pemb,
                      const float* __restrict__ g, const float* __restrict__ be,
                      float* __restrict__ h, u16* __restrict__ hb){
  __shared__ float s1[4], s2[4];
  int row = blockIdx.x, t = threadIdx.x;
  float* hr = h + (size_t)row * 768;
  const float* pr = pemb + (size_t)pos[row] * 768;
  float x0 = hr[t] + pr[t], x1 = hr[t+256] + pr[t+256], x2 = hr[t+512] + pr[t+512];
  float s = x0 + x1 + x2, q = x0*x0 + x1*x1 + x2*x2;
  for (int o = 32; o; o >>= 1){ s += __shfl_down(s, o, 64); q += __shfl_down(q, o, 64); }
  int wv = t >> 6, ln = t & 63;
  if (!ln){ s1[wv] = s; s2[wv] = q; }
  __syncthreads();
  s = s1[0]+s1[1]+s1[2]+s1[3]; q = s2[0]+s2[1]+s2[2]+s2[3];
  float mu = s * (1.f/768.f);
  float rs = rsqrtf(q * (1.f/768.f) - mu*mu + 1e-5f);
  u16* hbr = hb + (size_t)row * 768;
  float y;
  y = (x0-mu)*rs*g[t]     + be[t];     hr[t]     = y; hbr[t]     = f2bf(y);
  y = (x1-mu)*rs*g[t+256] + be[t+256]; hr[t+256] = y; hbr[t+256] = f2bf(y);
  y = (x2-mu)*rs*g[t+512] + be[t+512]; hr[t+512] = y; hbr[t+512] = f2bf(y);
}

__global__ void k_lnres(const float* __restrict__ C, const float* __restrict__ g,
                        const float* __restrict__ be, float* __restrict__ h,
                        u16* __restrict__ hb){
  __shared__ float s1[4], s2[4];
  int row = blockIdx.x, t = threadIdx.x;
  float* hr = h + (size_t)row * 768;
  const float* cr = C + (size_t)row * 768;
  float x0 = hr[t] + cr[t], x1 = hr[t+256] + cr[t+256], x2 = hr[t+512] + cr[t+512];
  float s = x0 + x1 + x2, q = x0*x0 + x1*x1 + x2*x2;
  for (int o = 32; o; o >>= 1){ s += __shfl_down(s, o, 64); q += __shfl_down(q, o, 64); }
  int wv = t >> 6, ln = t & 63;
  if (!ln){ s1[wv] = s; s2[wv] = q; }
  __syncthreads();
  s = s1[0]+s1[1]+s1[2]+s1[3]; q = s2[0]+s2[1]+s2[2]+s2[3];
  float mu = s * (1.f/768.f);
  float rs = rsqrtf(q * (1.f/768.f) - mu*mu + 1e-5f);
  u16* hbr = hb + (size_t)row * 768;
  float y;
  y = (x0-mu)*rs*g[t]     + be[t];     hr[t]     = y; hbr[t]     = f2bf(y);
  y = (x1-mu)*rs*g[t+256] + be[t+256]; hr[t+256] = y; hbr[t+256] = f2bf(y);
  y = (x2-mu)*rs*g[t+512] + be[t+512]; hr[t+512] = y; hbr[t+512] = f2bf(y);
}

// ---------------- weight transpose+cast: src[K][N] f32 -> dst[N][K] bf16 ----------------
__global__ void k_transpose(const float* __restrict__ src, u16* __restrict__ dst,
                            int K, int N){
  __shared__ float tile[32][33];
  int k0 = blockIdx.x * 32, n0 = blockIdx.y * 32;
  int tx = threadIdx.x & 31, ty = threadIdx.x >> 5;   // ty 0..7
  #pragma unroll
  for (int i = 0; i < 32; i += 8)
    tile[ty + i][tx] = src[(size_t)(k0 + ty + i) * N + n0 + tx];
  __syncthreads();
  #pragma unroll
  for (int i = 0; i < 32; i += 8)
    dst[(size_t)(n0 + ty + i) * K + k0 + tx] = f2bf(tile[tx][ty + i]);
}

// ================== 256x256 8-phase GEMM (T1+T2+T3+T4+T5), BT = [N][K] ==================
// EPI 0: bf16 out + bias; 1: f32 out + bias; 2: bf16 + bias + GELU;
// EPI 3: qkv scatter -> head-packed q/k/v buffers [b*12+h][512][64] bf16

DEVI void stage_half(const u16* __restrict__ P, int row0, int K, int kt, int h,
                     int boff, u16* sm, int w, int lane){
  #pragma unroll
  for (int j = 0; j < 2; j++){
    int ob = ((w*2 + j) << 10);          // wave-uniform byte offset within half
    int o  = ob + lane*16;
    int r  = (h << 7) + (o >> 7);
    int c  = ((o >> 4) & 7) ^ (r & 7);   // inverse-swizzled source chunk
    gload16(P + (size_t)(row0 + r)*K + (size_t)kt*64 + c*8,
            &sm[boff + (h << 13) + (ob >> 1)]);
  }
}

#define BAR() do { asm volatile("s_barrier" ::: "memory"); \
                   __builtin_amdgcn_sched_barrier(0); } while(0)

template<int EPI>
__global__ __launch_bounds__(512, 2)
void k_gemm2(const u16* __restrict__ A, const u16* __restrict__ BT,
             const float* __restrict__ bias, void* __restrict__ out,
             int M, int N, int K){
  __shared__ __align__(16) u16 sm[65536];   // 128 KiB
  const int tid = threadIdx.x;
  const int w = tid >> 6, lane = tid & 63;
  const int wm = w >> 2, wn = w & 3;
  const int cr = lane & 15, cg = lane >> 4;

  // bijective XCD-chunked remap (m204)
  const int nbn = gridDim.x;
  const int nwg = nbn * gridDim.y;
  const int d   = blockIdx.y * nbn + blockIdx.x;
  const int xcd = d & 7, qq = nwg >> 3, rr = nwg & 7;
  const int logical = (xcd < rr ? xcd*(qq+1) : rr*(qq+1) + (xcd-rr)*qq) + (d >> 3);
  const int m0 = (logical / nbn) * 256;
  const int n0 = (logical % nbn) * 256;

  const int NT = K >> 6;
  const int rowA = wm*128 + cr;
  const int rowB = wn*64  + cr;
  int slot[2];
  slot[0] = ((cg     ^ (cr & 7)) << 3);
  slot[1] = (((4+cg) ^ (cr & 7)) << 3);

  f32x4 acc[8][4] = {};
  bf16x8 bfr[4][2], afr[2][2];

#define LOADA(mf0) \
  _Pragma("unroll") for (int i = 0; i < 2; i++) \
    _Pragma("unroll") for (int s = 0; s < 2; s++) \
      afr[i][s] = *(const bf16x8*)&sm[ab + (rowA + ((mf0)+i)*16)*64 + slot[s]];

#define FMA2(mf0) \
  __builtin_amdgcn_s_setprio(1); \
  _Pragma("unroll") for (int n = 0; n < 4; n++){ \
    acc[(mf0)][n]   = MFMA(afr[0][0], bfr[n][0], acc[(mf0)][n]); \
    acc[(mf0)][n]   = MFMA(afr[0][1], bfr[n][1], acc[(mf0)][n]); \
    acc[(mf0)+1][n] = MFMA(afr[1][0], bfr[n][0], acc[(mf0)+1][n]); \
    acc[(mf0)+1][n] = MFMA(afr[1][1], bfr[n][1], acc[(mf0)+1][n]); \
  } \
  __builtin_amdgcn_s_setprio(0);

  // ---- prologue: tile0 (A+B) into buf0, B of tile1 into buf1
  stage_half(A,  m0, K, 0, 0, 0,     sm, w, lane);
  stage_half(A,  m0, K, 0, 1, 0,     sm, w, lane);
  stage_half(BT, n0, K, 0, 0, 32768, sm, w, lane);
  stage_half(BT, n0, K, 0, 1, 32768, sm, w, lane);
  if (NT > 1){
    stage_half(BT, n0, K, 1, 0, 32768+16384, sm, w, lane);
    stage_half(BT, n0, K, 1, 1, 32768+16384, sm, w, lane);
    asm volatile("s_waitcnt vmcnt(4)" ::: "memory");
  } else {
    asm volatile("s_waitcnt vmcnt(0)" ::: "memory");
  }
  __builtin_amdgcn_sched_barrier(0);
  BAR();

  for (int t = 0; t < NT; ++t){
    const int ab  = (t & 1) << 14;
    const int bb  = 32768 + ab;
    const int nb1 = ((t + 1) & 1) << 14;

    // ---- phase 0: all B-frags + A mf0-1; stage A0(t+1)
    #pragma unroll
    for (int n = 0; n < 4; n++)
      #pragma unroll
      for (int s = 0; s < 2; s++)
        bfr[n][s] = *(const bf16x8*)&sm[bb + (rowB + n*16)*64 + slot[s]];
    LOADA(0);
    if (t + 1 < NT) stage_half(A, m0, K, t+1, 0, nb1, sm, w, lane);
    BAR();
    FMA2(0);
    BAR();

    // ---- phase 1: A mf2-3; stage A1(t+1)
    LOADA(2);
    if (t + 1 < NT) stage_half(A, m0, K, t+1, 1, nb1, sm, w, lane);
    BAR();
    FMA2(2);
    BAR();

    // ---- phase 2: A mf4-5; stage B0(t+2)
    LOADA(4);
    if (t + 2 < NT) stage_half(BT, n0, K, t+2, 0, bb, sm, w, lane);
    BAR();
    FMA2(4);
    BAR();

    // ---- phase 3: A mf6-7; stage B1(t+2); counted vmcnt once per K-tile
    LOADA(6);
    if (t + 2 < NT) stage_half(BT, n0, K, t+2, 1, bb, sm, w, lane);
    BAR();
    FMA2(6);
    if (t + 2 < NT) { asm volatile("s_waitcnt vmcnt(4)" ::: "memory"); }
    else            { asm volatile("s_waitcnt vmcnt(0)" ::: "memory"); }
    __builtin_amdgcn_sched_barrier(0);
    BAR();
  }

  // ---- epilogue
  #pragma unroll
  for (int n = 0; n < 4; n++){
    int col = n0 + wn*64 + n*16 + cr;
    float bv = bias[col];
    int sec = 0, hd = 0, dcol = 0;
    if (EPI == 3){
      sec = (col >= 1536) ? 2 : (col >= 768 ? 1 : 0);
      hd  = (col - sec*768) >> 6;
      dcol = col & 63;
    }
    #pragma unroll
    for (int mf = 0; mf < 8; mf++){
      #pragma unroll
      for (int j = 0; j < 4; j++){
        int row = m0 + wm*128 + mf*16 + cg*4 + j;
        float v = acc[mf][n][j] + bv;
        if (EPI == 2) v = 0.5f * v * (1.f + erff(v * 0.70710678118654752f));
        if (EPI == 1)      ((float*)out)[(size_t)row * N + col] = v;
        else if (EPI == 3){
          int b = row >> 9, s = row & 511;
          ((u16*)out)[(size_t)sec*25165824 + (((size_t)(b*12 + hd)*512 + s) << 6) + dcol] = f2bf(v);
        }
        else               ((u16*) out)[(size_t)row * N + col] = f2bf(v);
      }
    }
  }
#undef LOADA
#undef FMA2
}

// ---------------- V^T repack: vbuf[bh][512][64] -> vt[bh][64][512] ----------------
__global__ void k_vtrep(const u16* __restrict__ vbuf, u16* __restrict__ vt){
  __shared__ u16 tile[64][72];
  int bh = blockIdx.y;               // b*12+h
  int t0 = blockIdx.x * 64;
  int tid = threadIdx.x;
  #pragma unroll
  for (int i = 0; i < 16; i++){
    int idx = tid + i * 256;
    int tt = idx >> 6, d = idx & 63;
    tile[tt][d] = vbuf[((size_t)bh * 512 + t0 + tt) * 64 + d];
  }
  __syncthreads();
  #pragma unroll
  for (int i = 0; i < 16; i++){
    int idx = tid + i * 256;
    int d = idx >> 6, tt = idx & 63;
    vt[((size_t)bh * 64 + d) * 512 + t0 + tt] = tile[tt][d];
  }
}

// ---------------- fused attention: one block per (qtile32, head, batch) ----------------
// qp/kp: [bh][512][64] bf16 packed; vt: [bh][64][512]
__global__ __launch_bounds__(256)
void k_attn(const u16* __restrict__ qp, const u16* __restrict__ kp,
            const u16* __restrict__ vt, const u32* __restrict__ mb,
            u16* __restrict__ ctx){
  __shared__ __align__(16) u16 P[32 * 520];
  __shared__ float red[2][4][32];
  const int tid = threadIdx.x, wv = tid >> 6, lane = tid & 63;
  const int cr = lane & 15, cg = lane >> 4;
  const int q0 = blockIdx.x * 32;
  const int h  = blockIdx.y;
  const int b  = blockIdx.z;
  const int bh = b * 12 + h;
  const size_t qb = (size_t)bh * 512 * 64;

  bf16x8 qf[2][2];
  #pragma unroll
  for (int m = 0; m < 2; m++)
    #pragma unroll
    for (int ks = 0; ks < 2; ks++)
      qf[m][ks] = *(const bf16x8*)&qp[qb + (size_t)(q0 + m*16 + cr) * 64 + ks*32 + cg*8];

  f32x4 acc[2][8] = {};
  #pragma unroll
  for (int n = 0; n < 8; n++){
    #pragma unroll
    for (int ks = 0; ks < 2; ks++){
      bf16x8 kf = *(const bf16x8*)&kp[qb + (size_t)(wv*128 + n*16 + cr) * 64 + ks*32 + cg*8];
      #pragma unroll
      for (int m = 0; m < 2; m++)
        acc[m][n] = MFMA(qf[m][ks], kf, acc[m][n]);
    }
  }

  // scale + mask bias + row max
  const u32* mbase = mb + ((size_t)b * 512 + q0) * 16 + wv * 4;
  #pragma unroll
  for (int m = 0; m < 2; m++){
    #pragma unroll
    for (int j = 0; j < 4; j++){
      int row = m*16 + cg*4 + j;
      const u32* mrow = mbase + (size_t)row * 16;
      float rm = -3e38f;
      #pragma unroll
      for (int n = 0; n < 8; n++){
        u32 wmask = mrow[n >> 1];
        float v = acc[m][n][j] * 0.125f + (((wmask >> ((n & 1) * 16 + cr)) & 1) ? 0.f : -10000.f);
        acc[m][n][j] = v;
        rm = fmaxf(rm, v);
      }
      #pragma unroll
      for (int s = 1; s < 16; s <<= 1) rm = fmaxf(rm, __shfl_xor(rm, s, 64));
      if (cr == 0) red[0][wv][row] = rm;
    }
  }
  __syncthreads();
  #pragma unroll
  for (int m = 0; m < 2; m++){
    #pragma unroll
    for (int j = 0; j < 4; j++){
      int row = m*16 + cg*4 + j;
      float gm = fmaxf(fmaxf(red[0][0][row], red[0][1][row]),
                       fmaxf(red[0][2][row], red[0][3][row]));
      float rs = 0.f;
      #pragma unroll
      for (int n = 0; n < 8; n++){
        float p = __expf(acc[m][n][j] - gm);
        rs += p;
        P[row * 520 + wv*128 + n*16 + cr] = f2bf(p);
      }
      #pragma unroll
      for (int s = 1; s < 16; s <<= 1) rs += __shfl_xor(rs, s, 64);
      if (cr == 0) red[1][wv][row] = rs;
    }
  }
  __syncthreads();

  // PV: each wave computes 32 rows x 16 d-cols (d = wv*16 + cr)
  const size_t vtb = (size_t)bh * 64;
  f32x4 pv[2] = {};
  #pragma unroll
  for (int kk = 0; kk < 16; kk++){
    bf16x8 vf = *(const bf16x8*)&vt[(vtb + wv*16 + cr) * 512 + kk*32 + cg*8];
    #pragma unroll
    for (int m = 0; m < 2; m++){
      bf16x8 pf = *(const bf16x8*)&P[(m*16 + cr) * 520 + kk*32 + cg*8];
      pv[m] = MFMA(pf, vf, pv[m]);
    }
  }
  #pragma unroll
  for (int m = 0; m < 2; m++){
    #pragma unroll
    for (int j = 0; j < 4; j++){
      int row = m*16 + cg*4 + j;
      float dsum = red[1][0][row] + red[1][1][row] + red[1][2][row] + red[1][3][row];
      float v = pv[m][j] / dsum;
      ctx[((size_t)b * 512 + q0 + row) * 768 + h*64 + wv*16 + cr] = f2bf(v);
    }
  }
}

// ---------------- head: dense+tanh then scalar logit ----------------
__global__ void k_dense(const float* __restrict__ h, const float* __restrict__ W,
                        const float* __restrict__ bias, float* __restrict__ xt){
  __shared__ float xs[768];
  int b = blockIdx.x, t = threadIdx.x;
  const float* hr = h + (size_t)b * 512 * 768;
  xs[t] = hr[t]; xs[t+256] = hr[t+256]; xs[t+512] = hr[t+512];
  __syncthreads();
  for (int j = t; j < 768; j += 256){
    float a = bias[j];
    #pragma unroll 4
    for (int k = 0; k < 768; k++) a += xs[k] * W[(size_t)k * 768 + j];
    xt[(size_t)b * 768 + j] = tanhf(a);
  }
}

__global__ void k_logits(const float* __restrict__ xt, const float* __restrict__ ow,
                         const float* __restrict__ ob, float* __restrict__ out){
  __shared__ float sb[4];
  int b = blockIdx.x, t = threadIdx.x;
  const float* x = xt + (size_t)b * 768;
  float s = x[t]*ow[t] + x[t+256]*ow[t+256] + x[t+512]*ow[t+512];
  for (int o = 32; o; o >>= 1) s += __shfl_down(s, o, 64);
  int wv = t >> 6, ln = t & 63;
  if (!ln) sb[wv] = s;
  __syncthreads();
  if (t == 0) out[b] = sb[0] + sb[1] + sb[2] + sb[3] + ob[0];
}

// ---------------- launch ----------------
extern "C" void kernel_launch(void* const* d_in, const int* in_sizes, int n_in,
                              void* d_out, int out_size, void* d_ws, size_t ws_size,
                              hipStream_t stream){
  if (n_in < 23) return;
  if (ws_size < 534000000ull) return;

  const int*   ids  = (const int*)  d_in[0];
  const int*   pos  = (const int*)  d_in[1];
  const void*  amsk =               d_in[2];
  const float* wemb = (const float*)d_in[3];
  const float* pemb = (const float*)d_in[4];
  const float* lng  = (const float*)d_in[5];
  const float* lnb  = (const float*)d_in[6];
  const float* Wqkv = (const float*)d_in[7];
  const float* bqkv = (const float*)d_in[8];
  const float* Wo   = (const float*)d_in[9];
  const float* bo   = (const float*)d_in[10];
  const float* ln1g = (const float*)d_in[11];
  const float* ln1b = (const float*)d_in[12];
  const float* W1   = (const float*)d_in[13];
  const float* b1   = (const float*)d_in[14];
  const float* W2   = (const float*)d_in[15];
  const float* b2   = (const float*)d_in[16];
  const float* ln2g = (const float*)d_in[17];
  const float* ln2b = (const float*)d_in[18];
  const float* dW   = (const float*)d_in[19];
  const float* db   = (const float*)d_in[20];
  const float* oW   = (const float*)d_in[21];
  const float* ob   = (const float*)d_in[22];

  char* ws = (char*)d_ws;
  float* h    = (float*)(ws);
  u16*   hb   = (u16*)  (ws + 100663296);
  float* C    = (float*)(ws + 150994944);
  u16*   qkvp = (u16*)  (ws + 251658240);   // qp | kp | vbuf, each 50331648 B
  u16*   vt   = (u16*)  (ws + 402653184);
  u16*   act  = (u16*)  (ws + 251658240);   // aliases qkvp+vt (disjoint lifetime)
  u16*   ctx  = (u16*)  (ws + 452984832);
  u32*   mbit = (u32*)  (ws + 503316480);
  u16*   wt   = (u16*)  (ws + 505413632);
  float* xt   = (float*)(ws + 533725184);
  int*   flag = (int*)  (ws + 533921792);

  u16* qp   = qkvp;
  u16* kp   = qkvp + (size_t)25165824;
  u16* vbuf = qkvp + (size_t)50331648;

  u16* WqkvT = wt;                                  // [l][2304][768]
  u16* WoT   = WqkvT + (size_t)2*2304*768;          // [l][768][768]
  u16* W1T   = WoT   + (size_t)2*768*768;           // [l][3072][768]
  u16* W2T   = W1T   + (size_t)2*3072*768;          // [l][768][3072]

  k_maskprobe<<<1, 256, 0, stream>>>((const unsigned char*)amsk, flag);
  k_maskbits<<<8192, 256, 0, stream>>>(amsk, flag, mbit);

  for (int l = 0; l < 2; l++){
    k_transpose<<<dim3(24, 72), 256, 0, stream>>>(Wqkv + (size_t)l*768*2304, WqkvT + (size_t)l*2304*768, 768, 2304);
    k_transpose<<<dim3(24, 24), 256, 0, stream>>>(Wo   + (size_t)l*768*768,  WoT   + (size_t)l*768*768,  768, 768);
    k_transpose<<<dim3(24, 96), 256, 0, stream>>>(W1   + (size_t)l*768*3072, W1T   + (size_t)l*3072*768, 768, 3072);
    k_transpose<<<dim3(96, 24), 256, 0, stream>>>(W2   + (size_t)l*3072*768, W2T   + (size_t)l*768*3072, 3072, 768);
  }

  k_embed<<<32768, 256, 0, stream>>>(ids, wemb, h);
  k_nodeavg<<<dim3(32768, 3), 256, 0, stream>>>(pos, mbit, h);
  k_ln0<<<32768, 256, 0, stream>>>(pos, pemb, lng, lnb, h, hb);

  for (int l = 0; l < 2; l++){
    k_gemm2<3><<<dim3(9, 128), 512, 0, stream>>>(hb, WqkvT + (size_t)l*2304*768, bqkv + l*2304, (void*)qkvp, 32768, 2304, 768);
    k_vtrep<<<dim3(8, 768), 256, 0, stream>>>(vbuf, vt);
    k_attn<<<dim3(16, 12, 64), 256, 0, stream>>>(qp, kp, vt, mbit, ctx);
    k_gemm2<1><<<dim3(3, 128), 512, 0, stream>>>(ctx, WoT + (size_t)l*768*768, bo + l*768, (void*)C, 32768, 768, 768);
    k_lnres<<<32768, 256, 0, stream>>>(C, ln1g + l*768, ln1b + l*768, h, hb);
    k_gemm2<2><<<dim3(12, 128), 512, 0, stream>>>(hb, W1T + (size_t)l*3072*768, b1 + l*3072, (void*)act, 32768, 3072, 768);
    k_gemm2<1><<<dim3(3, 128), 512, 0, stream>>>(act, W2T + (size_t)l*768*3072, b2 + l*768, (void*)C, 32768, 768, 3072);
    k_lnres<<<32768, 256, 0, stream>>>(C, ln2g + l*768, ln2b + l*768, h, hb);
  }

  k_dense<<<64, 256, 0, stream>>>(h, dW, db, xt);
  k_logits<<<64, 256, 0, stream>>>(xt, oW, ob, (float*)d_out);
}

// Round 5
// 2697.504 us; speedup vs baseline: 1.0127x; 1.0127x over previous
//
#include <hip/hip_runtime.h>

typedef unsigned short u16;
typedef unsigned int   u32;
typedef __bf16 bf16x8 __attribute__((ext_vector_type(8)));
typedef float  f32x4  __attribute__((ext_vector_type(4)));

#define DEVI __device__ __forceinline__

DEVI u16 f2bf(float f){
  u32 u = __builtin_bit_cast(u32, f);
  u32 r = (u + 0x7fffu + ((u >> 16) & 1u)) >> 16;   // RNE
  return (u16)r;
}

DEVI void gload16(const void* g, void* lds){
  __builtin_amdgcn_global_load_lds(
      (const __attribute__((address_space(1))) void*)g,
      (__attribute__((address_space(3))) void*)lds, 16, 0, 0);
}

DEVI f32x4 MFMA(bf16x8 a, bf16x8 b, f32x4 c){
  return __builtin_amdgcn_mfma_f32_16x16x32_bf16(a, b, c, 0, 0, 0);
}

// ---------------- mask dtype probe: 1 => uint8 bytes, 0 => int32 ----------------
__global__ void k_maskprobe(const unsigned char* __restrict__ m, int* __restrict__ flag){
  __shared__ int s;
  if (threadIdx.x == 0) s = 0;
  __syncthreads();
  int acc = 0;
  for (int i = threadIdx.x; i < 65536; i += 256)
    if ((i & 3) != 0 && m[i] != 0) acc++;
  atomicAdd(&s, acc);
  __syncthreads();
  if (threadIdx.x == 0) *flag = (s > 0) ? 1 : 0;
}

// ---------------- pack attn_mask to bitmask [B*S][16 words] ----------------
__global__ void k_maskbits(const void* __restrict__ mask, const int* __restrict__ flag,
                           u32* __restrict__ mb){
  int row  = blockIdx.x * 4 + (threadIdx.x >> 6);   // b*512+q
  int lane = threadIdx.x & 63;
  bool bytes = (*flag != 0);
  for (int c0 = 0; c0 < 512; c0 += 64){
    int v;
    if (bytes) v = ((const unsigned char*)mask)[(size_t)row * 512 + c0 + lane];
    else       v = ((const int*)mask)[(size_t)row * 512 + c0 + lane];
    unsigned long long bits = __ballot(v != 0);
    if (lane == 0){
      mb[(size_t)row * 16 + (c0 >> 5)]     = (u32)(bits & 0xffffffffull);
      mb[(size_t)row * 16 + (c0 >> 5) + 1] = (u32)(bits >> 32);
    }
  }
}

// ---------------- embedding gather ----------------
__global__ void k_embed(const int* __restrict__ ids, const float* __restrict__ wemb,
                        float* __restrict__ h){
  int row = blockIdx.x;
  const float* s = wemb + (size_t)ids[row] * 768;
  float* d = h + (size_t)row * 768;
  int t = threadIdx.x;
  d[t] = s[t]; d[t + 256] = s[t + 256]; d[t + 512] = s[t + 512];
}

// ---------------- node-average (rows with pos==0) ----------------
__global__ void k_nodeavg(const int* __restrict__ pos, const u32* __restrict__ mb,
                          float* __restrict__ h){
  int row = blockIdx.x;                 // b*512+n
  if (pos[row] != 0) return;
  int b = row >> 9;
  int c = blockIdx.y * 256 + threadIdx.x;
  const u32* mrow = mb + (size_t)row * 16;
  const int* pb = pos + ((size_t)b << 9);
  float a = 0.f, cnt = 0.f;
  #pragma unroll 4
  for (int t = 0; t < 512; t++){
    if (pb[t] >= 2 && ((mrow[t >> 5] >> (t & 31)) & 1)){
      a += h[(((size_t)b << 9) + t) * 768 + c];
      cnt += 1.f;
    }
  }
  h[(size_t)row * 768 + c] = a / (cnt + 1e-10f);
}

// ---------------- LN kernels ----------------
__global__ void k_ln0(const int* __restrict__ pos, const float* __restrict__ pemb,
                      const float* __restrict__ g, const float* __restrict__ be,
                      float* __restrict__ h, u16* __restrict__ hb){
  __shared__ float s1[4], s2[4];
  int row = blockIdx.x, t = threadIdx.x;
  float* hr = h + (size_t)row * 768;
  const float* pr = pemb + (size_t)pos[row] * 768;
  float x0 = hr[t] + pr[t], x1 = hr[t+256] + pr[t+256], x2 = hr[t+512] + pr[t+512];
  float s = x0 + x1 + x2, q = x0*x0 + x1*x1 + x2*x2;
  for (int o = 32; o; o >>= 1){ s += __shfl_down(s, o, 64); q += __shfl_down(q, o, 64); }
  int wv = t >> 6, ln = t & 63;
  if (!ln){ s1[wv] = s; s2[wv] = q; }
  __syncthreads();
  s = s1[0]+s1[1]+s1[2]+s1[3]; q = s2[0]+s2[1]+s2[2]+s2[3];
  float mu = s * (1.f/768.f);
  float rs = rsqrtf(q * (1.f/768.f) - mu*mu + 1e-5f);
  u16* hbr = hb + (size_t)row * 768;
  float y;
  y = (x0-mu)*rs*g[t]     + be[t];     hr[t]     = y; hbr[t]     = f2bf(y);
  y = (x1-mu)*rs*g[t+256] + be[t+256]; hr[t+256] = y; hbr[t+256] = f2bf(y);
  y = (x2-mu)*rs*g[t+512] + be[t+512]; hr[t+512] = y; hbr[t+512] = f2bf(y);
}

__global__ void k_lnres(const float* __restrict__ C, const float* __restrict__ g,
                        const float* __restrict__ be, float* __restrict__ h,
                        u16* __restrict__ hb){
  __shared__ float s1[4], s2[4];
  int row = blockIdx.x, t = threadIdx.x;
  float* hr = h + (size_t)row * 768;
  const float* cr = C + (size_t)row * 768;
  float x0 = hr[t] + cr[t], x1 = hr[t+256] + cr[t+256], x2 = hr[t+512] + cr[t+512];
  float s = x0 + x1 + x2, q = x0*x0 + x1*x1 + x2*x2;
  for (int o = 32; o; o >>= 1){ s += __shfl_down(s, o, 64); q += __shfl_down(q, o, 64); }
  int wv = t >> 6, ln = t & 63;
  if (!ln){ s1[wv] = s; s2[wv] = q; }
  __syncthreads();
  s = s1[0]+s1[1]+s1[2]+s1[3]; q = s2[0]+s2[1]+s2[2]+s2[3];
  float mu = s * (1.f/768.f);
  float rs = rsqrtf(q * (1.f/768.f) - mu*mu + 1e-5f);
  u16* hbr = hb + (size_t)row * 768;
  float y;
  y = (x0-mu)*rs*g[t]     + be[t];     hr[t]     = y; hbr[t]     = f2bf(y);
  y = (x1-mu)*rs*g[t+256] + be[t+256]; hr[t+256] = y; hbr[t+256] = f2bf(y);
  y = (x2-mu)*rs*g[t+512] + be[t+512]; hr[t+512] = y; hbr[t+512] = f2bf(y);
}

// ---------------- weight transpose+cast: src[K][N] f32 -> dst[N][K] bf16 ----------------
__global__ void k_transpose(const float* __restrict__ src, u16* __restrict__ dst,
                            int K, int N){
  __shared__ float tile[32][33];
  int k0 = blockIdx.x * 32, n0 = blockIdx.y * 32;
  int tx = threadIdx.x & 31, ty = threadIdx.x >> 5;   // ty 0..7
  #pragma unroll
  for (int i = 0; i < 32; i += 8)
    tile[ty + i][tx] = src[(size_t)(k0 + ty + i) * N + n0 + tx];
  __syncthreads();
  #pragma unroll
  for (int i = 0; i < 32; i += 8)
    dst[(size_t)(n0 + ty + i) * K + k0 + tx] = f2bf(tile[tx][ty + i]);
}

// ================== 256x256 8-phase GEMM (T1+T2+T3+T4+T5), BT = [N][K] ==================
// EPI 0: bf16 out + bias; 1: f32 out + bias; 2: bf16 + bias + GELU;
// EPI 3: qkv scatter -> head-packed q/k/v buffers [b*12+h][512][64] bf16

DEVI void stage_half(const u16* __restrict__ P, int row0, int K, int kt, int h,
                     int boff, u16* sm, int w, int lane){
  #pragma unroll
  for (int j = 0; j < 2; j++){
    int ob = ((w*2 + j) << 10);          // wave-uniform byte offset within half
    int o  = ob + lane*16;
    int r  = (h << 7) + (o >> 7);
    int c  = ((o >> 4) & 7) ^ (r & 7);   // inverse-swizzled source chunk
    gload16(P + (size_t)(row0 + r)*K + (size_t)kt*64 + c*8,
            &sm[boff + (h << 13) + (ob >> 1)]);
  }
}

#define BAR() do { asm volatile("s_barrier" ::: "memory"); \
                   __builtin_amdgcn_sched_barrier(0); } while(0)

template<int EPI>
__global__ __launch_bounds__(512, 2)
void k_gemm2(const u16* __restrict__ A, const u16* __restrict__ BT,
             const float* __restrict__ bias, void* __restrict__ out,
             int M, int N, int K){
  __shared__ __align__(16) u16 sm[65536];   // 128 KiB
  const int tid = threadIdx.x;
  const int w = tid >> 6, lane = tid & 63;
  const int wm = w >> 2, wn = w & 3;
  const int cr = lane & 15, cg = lane >> 4;

  // bijective XCD-chunked remap (m204)
  const int nbn = gridDim.x;
  const int nwg = nbn * gridDim.y;
  const int d   = blockIdx.y * nbn + blockIdx.x;
  const int xcd = d & 7, qq = nwg >> 3, rr = nwg & 7;
  const int logical = (xcd < rr ? xcd*(qq+1) : rr*(qq+1) + (xcd-rr)*qq) + (d >> 3);
  const int m0 = (logical / nbn) * 256;
  const int n0 = (logical % nbn) * 256;

  const int NT = K >> 6;
  const int rowA = wm*128 + cr;
  const int rowB = wn*64  + cr;
  int slot[2];
  slot[0] = ((cg     ^ (cr & 7)) << 3);
  slot[1] = (((4+cg) ^ (cr & 7)) << 3);

  f32x4 acc[8][4] = {};
  bf16x8 bfr[4][2], afr[2][2];

#define LOADA(mf0) \
  _Pragma("unroll") for (int i = 0; i < 2; i++) \
    _Pragma("unroll") for (int s = 0; s < 2; s++) \
      afr[i][s] = *(const bf16x8*)&sm[ab + (rowA + ((mf0)+i)*16)*64 + slot[s]];

#define FMA2(mf0) \
  __builtin_amdgcn_s_setprio(1); \
  _Pragma("unroll") for (int n = 0; n < 4; n++){ \
    acc[(mf0)][n]   = MFMA(afr[0][0], bfr[n][0], acc[(mf0)][n]); \
    acc[(mf0)][n]   = MFMA(afr[0][1], bfr[n][1], acc[(mf0)][n]); \
    acc[(mf0)+1][n] = MFMA(afr[1][0], bfr[n][0], acc[(mf0)+1][n]); \
    acc[(mf0)+1][n] = MFMA(afr[1][1], bfr[n][1], acc[(mf0)+1][n]); \
  } \
  __builtin_amdgcn_s_setprio(0);

  // ---- prologue: tile0 (A+B) into buf0, B of tile1 into buf1
  stage_half(A,  m0, K, 0, 0, 0,     sm, w, lane);
  stage_half(A,  m0, K, 0, 1, 0,     sm, w, lane);
  stage_half(BT, n0, K, 0, 0, 32768, sm, w, lane);
  stage_half(BT, n0, K, 0, 1, 32768, sm, w, lane);
  if (NT > 1){
    stage_half(BT, n0, K, 1, 0, 32768+16384, sm, w, lane);
    stage_half(BT, n0, K, 1, 1, 32768+16384, sm, w, lane);
    asm volatile("s_waitcnt vmcnt(4)" ::: "memory");
  } else {
    asm volatile("s_waitcnt vmcnt(0)" ::: "memory");
  }
  __builtin_amdgcn_sched_barrier(0);
  BAR();

  for (int t = 0; t < NT; ++t){
    const int ab  = (t & 1) << 14;
    const int bb  = 32768 + ab;
    const int nb1 = ((t + 1) & 1) << 14;

    // ---- phase 0: all B-frags + A mf0-1; stage A0(t+1)
    #pragma unroll
    for (int n = 0; n < 4; n++)
      #pragma unroll
      for (int s = 0; s < 2; s++)
        bfr[n][s] = *(const bf16x8*)&sm[bb + (rowB + n*16)*64 + slot[s]];
    LOADA(0);
    if (t + 1 < NT) stage_half(A, m0, K, t+1, 0, nb1, sm, w, lane);
    BAR();
    FMA2(0);
    BAR();

    // ---- phase 1: A mf2-3; stage A1(t+1)
    LOADA(2);
    if (t + 1 < NT) stage_half(A, m0, K, t+1, 1, nb1, sm, w, lane);
    BAR();
    FMA2(2);
    BAR();

    // ---- phase 2: A mf4-5; stage B0(t+2)
    LOADA(4);
    if (t + 2 < NT) stage_half(BT, n0, K, t+2, 0, bb, sm, w, lane);
    BAR();
    FMA2(4);
    BAR();

    // ---- phase 3: A mf6-7; stage B1(t+2); counted vmcnt once per K-tile
    LOADA(6);
    if (t + 2 < NT) stage_half(BT, n0, K, t+2, 1, bb, sm, w, lane);
    BAR();
    FMA2(6);
    if (t + 2 < NT) { asm volatile("s_waitcnt vmcnt(4)" ::: "memory"); }
    else            { asm volatile("s_waitcnt vmcnt(0)" ::: "memory"); }
    __builtin_amdgcn_sched_barrier(0);
    BAR();
  }

  // ---- epilogue
  #pragma unroll
  for (int n = 0; n < 4; n++){
    int col = n0 + wn*64 + n*16 + cr;
    float bv = bias[col];
    int sec = 0, hd = 0, dcol = 0;
    if (EPI == 3){
      sec = (col >= 1536) ? 2 : (col >= 768 ? 1 : 0);
      hd  = (col - sec*768) >> 6;
      dcol = col & 63;
    }
    #pragma unroll
    for (int mf = 0; mf < 8; mf++){
      #pragma unroll
      for (int j = 0; j < 4; j++){
        int row = m0 + wm*128 + mf*16 + cg*4 + j;
        float v = acc[mf][n][j] + bv;
        if (EPI == 2) v = 0.5f * v * (1.f + erff(v * 0.70710678118654752f));
        if (EPI == 1)      ((float*)out)[(size_t)row * N + col] = v;
        else if (EPI == 3){
          int b = row >> 9, s = row & 511;
          ((u16*)out)[(size_t)sec*25165824 + (((size_t)(b*12 + hd)*512 + s) << 6) + dcol] = f2bf(v);
        }
        else               ((u16*) out)[(size_t)row * N + col] = f2bf(v);
      }
    }
  }
#undef LOADA
#undef FMA2
}

// ---------------- V^T repack: vbuf[bh][512][64] -> vt[bh][64][512] ----------------
__global__ void k_vtrep(const u16* __restrict__ vbuf, u16* __restrict__ vt){
  __shared__ u16 tile[64][72];
  int bh = blockIdx.y;               // b*12+h
  int t0 = blockIdx.x * 64;
  int tid = threadIdx.x;
  #pragma unroll
  for (int i = 0; i < 16; i++){
    int idx = tid + i * 256;
    int tt = idx >> 6, d = idx & 63;
    tile[tt][d] = vbuf[((size_t)bh * 512 + t0 + tt) * 64 + d];
  }
  __syncthreads();
  #pragma unroll
  for (int i = 0; i < 16; i++){
    int idx = tid + i * 256;
    int d = idx >> 6, tt = idx & 63;
    vt[((size_t)bh * 64 + d) * 512 + t0 + tt] = tile[tt][d];
  }
}

// ---------------- fused attention: one block per (qtile32, head, batch) ----------------
// qp/kp: [bh][512][64] bf16 packed; vt: [bh][64][512]
// T1: XCD-chunked remap so all 16 q-tiles of a head land on one XCD (K/V L2 reuse).
// P-LDS stored with 16B-chunk XOR swizzle: chunk c of row r at slot c^(r&7).
__global__ __launch_bounds__(256)
void k_attn(const u16* __restrict__ qp, const u16* __restrict__ kp,
            const u16* __restrict__ vt, const u32* __restrict__ mb,
            u16* __restrict__ ctx){
  __shared__ __align__(16) u16 P[32 * 512];
  __shared__ float red[2][4][32];
  const int tid = threadIdx.x, wv = tid >> 6, lane = tid & 63;
  const int cr = lane & 15, cg = lane >> 4;

  // XCD-chunked remap: grid (16,12,64) -> 12288 blocks, 12288%8==0
  const int nwg = gridDim.x * gridDim.y * gridDim.z;
  const int dd  = blockIdx.x + gridDim.x * (blockIdx.y + gridDim.y * blockIdx.z);
  const int qq_ = nwg >> 3;
  const int logical = (dd & 7) * qq_ + (dd >> 3);
  const int q0 = (logical & 15) * 32;
  const int h  = (logical >> 4) % 12;
  const int b  = logical / 192;

  const int bh = b * 12 + h;
  const size_t qb = (size_t)bh * 512 * 64;

  bf16x8 qf[2][2];
  #pragma unroll
  for (int m = 0; m < 2; m++)
    #pragma unroll
    for (int ks = 0; ks < 2; ks++)
      qf[m][ks] = *(const bf16x8*)&qp[qb + (size_t)(q0 + m*16 + cr) * 64 + ks*32 + cg*8];

  f32x4 acc[2][8] = {};
  #pragma unroll
  for (int n = 0; n < 8; n++){
    #pragma unroll
    for (int ks = 0; ks < 2; ks++){
      bf16x8 kf = *(const bf16x8*)&kp[qb + (size_t)(wv*128 + n*16 + cr) * 64 + ks*32 + cg*8];
      #pragma unroll
      for (int m = 0; m < 2; m++)
        acc[m][n] = MFMA(qf[m][ks], kf, acc[m][n]);
    }
  }

  // scale + mask bias + row max
  const u32* mbase = mb + ((size_t)b * 512 + q0) * 16 + wv * 4;
  #pragma unroll
  for (int m = 0; m < 2; m++){
    #pragma unroll
    for (int j = 0; j < 4; j++){
      int row = m*16 + cg*4 + j;
      const u32* mrow = mbase + (size_t)row * 16;
      float rm = -3e38f;
      #pragma unroll
      for (int n = 0; n < 8; n++){
        u32 wmask = mrow[n >> 1];
        float v = acc[m][n][j] * 0.125f + (((wmask >> ((n & 1) * 16 + cr)) & 1) ? 0.f : -10000.f);
        acc[m][n][j] = v;
        rm = fmaxf(rm, v);
      }
      #pragma unroll
      for (int s = 1; s < 16; s <<= 1) rm = fmaxf(rm, __shfl_xor(rm, s, 64));
      if (cr == 0) red[0][wv][row] = rm;
    }
  }
  __syncthreads();
  #pragma unroll
  for (int m = 0; m < 2; m++){
    #pragma unroll
    for (int j = 0; j < 4; j++){
      int row = m*16 + cg*4 + j;
      float gm = fmaxf(fmaxf(red[0][0][row], red[0][1][row]),
                       fmaxf(red[0][2][row], red[0][3][row]));
      float rs = 0.f;
      #pragma unroll
      for (int n = 0; n < 8; n++){
        float p = __expf(acc[m][n][j] - gm);
        rs += p;
        // col = wv*128 + n*16 + cr; chunk = col>>3; slot = chunk ^ (row&7)
        int c16 = wv*16 + n*2 + (cr >> 3);
        P[row * 512 + ((c16 ^ (row & 7)) << 3) + (cr & 7)] = f2bf(p);
      }
      #pragma unroll
      for (int s = 1; s < 16; s <<= 1) rs += __shfl_xor(rs, s, 64);
      if (cr == 0) red[1][wv][row] = rs;
    }
  }
  __syncthreads();

  // PV: each wave computes 32 rows x 16 d-cols (d = wv*16 + cr)
  const size_t vtb = (size_t)bh * 64;
  f32x4 pv[2] = {};
  #pragma unroll
  for (int kk = 0; kk < 16; kk++){
    bf16x8 vf = *(const bf16x8*)&vt[(vtb + wv*16 + cr) * 512 + kk*32 + cg*8];
    #pragma unroll
    for (int m = 0; m < 2; m++){
      int row = m*16 + cr;
      bf16x8 pf = *(const bf16x8*)&P[row * 512 + (((kk*4 + cg) ^ (row & 7)) << 3)];
      pv[m] = MFMA(pf, vf, pv[m]);
    }
  }
  #pragma unroll
  for (int m = 0; m < 2; m++){
    #pragma unroll
    for (int j = 0; j < 4; j++){
      int row = m*16 + cg*4 + j;
      float dsum = red[1][0][row] + red[1][1][row] + red[1][2][row] + red[1][3][row];
      float v = pv[m][j] / dsum;
      ctx[((size_t)b * 512 + q0 + row) * 768 + h*64 + wv*16 + cr] = f2bf(v);
    }
  }
}

// ---------------- head: dense+tanh then scalar logit ----------------
__global__ void k_dense(const float* __restrict__ h, const float* __restrict__ W,
                        const float* __restrict__ bias, float* __restrict__ xt){
  __shared__ float xs[768];
  int b = blockIdx.x, t = threadIdx.x;
  const float* hr = h + (size_t)b * 512 * 768;
  xs[t] = hr[t]; xs[t+256] = hr[t+256]; xs[t+512] = hr[t+512];
  __syncthreads();
  for (int j = t; j < 768; j += 256){
    float a = bias[j];
    #pragma unroll 4
    for (int k = 0; k < 768; k++) a += xs[k] * W[(size_t)k * 768 + j];
    xt[(size_t)b * 768 + j] = tanhf(a);
  }
}

__global__ void k_logits(const float* __restrict__ xt, const float* __restrict__ ow,
                         const float* __restrict__ ob, float* __restrict__ out){
  __shared__ float sb[4];
  int b = blockIdx.x, t = threadIdx.x;
  const float* x = xt + (size_t)b * 768;
  float s = x[t]*ow[t] + x[t+256]*ow[t+256] + x[t+512]*ow[t+512];
  for (int o = 32; o; o >>= 1) s += __shfl_down(s, o, 64);
  int wv = t >> 6, ln = t & 63;
  if (!ln) sb[wv] = s;
  __syncthreads();
  if (t == 0) out[b] = sb[0] + sb[1] + sb[2] + sb[3] + ob[0];
}

// ---------------- launch ----------------
extern "C" void kernel_launch(void* const* d_in, const int* in_sizes, int n_in,
                              void* d_out, int out_size, void* d_ws, size_t ws_size,
                              hipStream_t stream){
  if (n_in < 23) return;
  if (ws_size < 534000000ull) return;

  const int*   ids  = (const int*)  d_in[0];
  const int*   pos  = (const int*)  d_in[1];
  const void*  amsk =               d_in[2];
  const float* wemb = (const float*)d_in[3];
  const float* pemb = (const float*)d_in[4];
  const float* lng  = (const float*)d_in[5];
  const float* lnb  = (const float*)d_in[6];
  const float* Wqkv = (const float*)d_in[7];
  const float* bqkv = (const float*)d_in[8];
  const float* Wo   = (const float*)d_in[9];
  const float* bo   = (const float*)d_in[10];
  const float* ln1g = (const float*)d_in[11];
  const float* ln1b = (const float*)d_in[12];
  const float* W1   = (const float*)d_in[13];
  const float* b1   = (const float*)d_in[14];
  const float* W2   = (const float*)d_in[15];
  const float* b2   = (const float*)d_in[16];
  const float* ln2g = (const float*)d_in[17];
  const float* ln2b = (const float*)d_in[18];
  const float* dW   = (const float*)d_in[19];
  const float* db   = (const float*)d_in[20];
  const float* oW   = (const float*)d_in[21];
  const float* ob   = (const float*)d_in[22];

  char* ws = (char*)d_ws;
  float* h    = (float*)(ws);
  u16*   hb   = (u16*)  (ws + 100663296);
  float* C    = (float*)(ws + 150994944);
  u16*   qkvp = (u16*)  (ws + 251658240);   // qp | kp | vbuf, each 50331648 B
  u16*   vt   = (u16*)  (ws + 402653184);
  u16*   act  = (u16*)  (ws + 251658240);   // aliases qkvp+vt (disjoint lifetime)
  u16*   ctx  = (u16*)  (ws + 452984832);
  u32*   mbit = (u32*)  (ws + 503316480);
  u16*   wt   = (u16*)  (ws + 505413632);
  float* xt   = (float*)(ws + 533725184);
  int*   flag = (int*)  (ws + 533921792);

  u16* qp   = qkvp;
  u16* kp   = qkvp + (size_t)25165824;
  u16* vbuf = qkvp + (size_t)50331648;

  u16* WqkvT = wt;                                  // [l][2304][768]
  u16* WoT   = WqkvT + (size_t)2*2304*768;          // [l][768][768]
  u16* W1T   = WoT   + (size_t)2*768*768;           // [l][3072][768]
  u16* W2T   = W1T   + (size_t)2*3072*768;          // [l][768][3072]

  k_maskprobe<<<1, 256, 0, stream>>>((const unsigned char*)amsk, flag);
  k_maskbits<<<8192, 256, 0, stream>>>(amsk, flag, mbit);

  for (int l = 0; l < 2; l++){
    k_transpose<<<dim3(24, 72), 256, 0, stream>>>(Wqkv + (size_t)l*768*2304, WqkvT + (size_t)l*2304*768, 768, 2304);
    k_transpose<<<dim3(24, 24), 256, 0, stream>>>(Wo   + (size_t)l*768*768,  WoT   + (size_t)l*768*768,  768, 768);
    k_transpose<<<dim3(24, 96), 256, 0, stream>>>(W1   + (size_t)l*768*3072, W1T   + (size_t)l*3072*768, 768, 3072);
    k_transpose<<<dim3(96, 24), 256, 0, stream>>>(W2   + (size_t)l*3072*768, W2T   + (size_t)l*768*3072, 3072, 768);
  }

  k_embed<<<32768, 256, 0, stream>>>(ids, wemb, h);
  k_nodeavg<<<dim3(32768, 3), 256, 0, stream>>>(pos, mbit, h);
  k_ln0<<<32768, 256, 0, stream>>>(pos, pemb, lng, lnb, h, hb);

  for (int l = 0; l < 2; l++){
    k_gemm2<3><<<dim3(9, 128), 512, 0, stream>>>(hb, WqkvT + (size_t)l*2304*768, bqkv + l*2304, (void*)qkvp, 32768, 2304, 768);
    k_vtrep<<<dim3(8, 768), 256, 0, stream>>>(vbuf, vt);
    k_attn<<<dim3(16, 12, 64), 256, 0, stream>>>(qp, kp, vt, mbit, ctx);
    k_gemm2<1><<<dim3(3, 128), 512, 0, stream>>>(ctx, WoT + (size_t)l*768*768, bo + l*768, (void*)C, 32768, 768, 768);
    k_lnres<<<32768, 256, 0, stream>>>(C, ln1g + l*768, ln1b + l*768, h, hb);
    k_gemm2<2><<<dim3(12, 128), 512, 0, stream>>>(hb, W1T + (size_t)l*3072*768, b1 + l*3072, (void*)act, 32768, 3072, 768);
    k_gemm2<1><<<dim3(3, 128), 512, 0, stream>>>(act, W2T + (size_t)l*768*3072, b2 + l*768, (void*)C, 32768, 768, 3072);
    k_lnres<<<32768, 256, 0, stream>>>(C, ln2g + l*768, ln2b + l*768, h, hb);
  }

  k_dense<<<64, 256, 0, stream>>>(h, dW, db, xt);
  k_logits<<<64, 256, 0, stream>>>(xt, oW, ob, (float*)d_out);
}